// Round 1
// baseline (267.156 us; speedup 1.0000x reference)
//
#include <hip/hip_runtime.h>
#include <math.h>
#include <float.h>

// Problem constants (fixed instance: B=8, D=256, N=2048)
#define BB 8
#define DD 256
#define NN 2048
#define MSPLIT 8
#define MRANGE (NN / MSPLIT)   // 256 m-columns per block
#define ROWS 64                // rows (n) per block
#define DCHUNK 8               // d-depth staged per iteration

// ---------------------------------------------------------------------------
// Kernel A: sq[b*N+n] = sum_d x[b,d,n]^2 in f64 (exact enough vs np float64).
// x layout (B, D, N): element (b,d,n) at b*D*N + d*N + n. Coalesced over n.
// ---------------------------------------------------------------------------
__global__ __launch_bounds__(256) void sq_kernel(const float* __restrict__ x,
                                                 double* __restrict__ sq) {
    int t = blockIdx.x * 256 + threadIdx.x;      // 0 .. B*N-1
    int b = t >> 11;                              // / NN
    int n = t & (NN - 1);
    const float* xb = x + (size_t)b * DD * NN + n;
    double s = 0.0;
#pragma unroll 8
    for (int d = 0; d < DD; ++d) {
        float v = xb[(size_t)d * NN];
        s += (double)v * (double)v;
    }
    sq[t] = s;
}

// ---------------------------------------------------------------------------
// Kernel B: for 64 rows x 256 m-columns, accumulate dot(a_n, x_m) over all
// 256 dims (f32 FMA), then per-row partial argmin of
//   d2 = max(sq[n] + sq[m] - 2*dot, 0)   (f64 combine; m==n masked)
// Thread tile: 8 rows x 8 m (acc[8][8]); block = 256 threads.
// ---------------------------------------------------------------------------
__global__ __launch_bounds__(256) void argmin_kernel(const float* __restrict__ x,
                                                     const double* __restrict__ sq,
                                                     double* __restrict__ pmin,
                                                     int* __restrict__ pidx) {
    __shared__ float As[DCHUNK][ROWS];    // 8 x 64  (2 KB)
    __shared__ float Bs[DCHUNK][MRANGE];  // 8 x 256 (8 KB)

    const int b  = blockIdx.z;
    const int n0 = blockIdx.x * ROWS;
    const int m0 = blockIdx.y * MRANGE;
    const int tid = threadIdx.x;
    const int mx = tid & 31;   // 0..31 -> m groups
    const int ry = tid >> 5;   // 0..7  -> row group (8 rows each)

    const float* xb = x + (size_t)b * DD * NN;

    float acc[8][8];
#pragma unroll
    for (int i = 0; i < 8; ++i)
#pragma unroll
        for (int j = 0; j < 8; ++j) acc[i][j] = 0.0f;

    for (int dc = 0; dc < DD / DCHUNK; ++dc) {
        const int dbase = dc * DCHUNK;
        // Stage A panel: 8 d x 64 rows = 512 floats, 2 per thread, coalesced.
#pragma unroll
        for (int k = 0; k < 2; ++k) {
            int idx = tid + k * 256;
            int dd = idx >> 6, r = idx & 63;
            As[dd][r] = xb[(size_t)(dbase + dd) * NN + n0 + r];
        }
        // Stage B panel: 8 d x 256 m = 2048 floats, 8 per thread, coalesced.
#pragma unroll
        for (int k = 0; k < 8; ++k) {
            int idx = tid + k * 256;
            int dd = idx >> 8, mm = idx & 255;
            Bs[dd][mm] = xb[(size_t)(dbase + dd) * NN + m0 + mm];
        }
        __syncthreads();

#pragma unroll
        for (int dd = 0; dd < DCHUNK; ++dd) {
            float4 a0 = *(const float4*)&As[dd][ry * 8];
            float4 a1 = *(const float4*)&As[dd][ry * 8 + 4];
            float4 b0 = *(const float4*)&Bs[dd][mx * 4];          // mt = 0
            float4 b1 = *(const float4*)&Bs[dd][128 + mx * 4];    // mt = 1
            const float av[8] = {a0.x, a0.y, a0.z, a0.w, a1.x, a1.y, a1.z, a1.w};
            const float bv[8] = {b0.x, b0.y, b0.z, b0.w, b1.x, b1.y, b1.z, b1.w};
#pragma unroll
            for (int i = 0; i < 8; ++i)
#pragma unroll
                for (int j = 0; j < 8; ++j)
                    acc[i][j] = fmaf(av[i], bv[j], acc[i][j]);
        }
        __syncthreads();
    }

    // Epilogue: per row, f64 distance combine + argmin over this block's 256 m.
    const double* sqb = sq + (size_t)b * NN;
#pragma unroll
    for (int i = 0; i < 8; ++i) {
        const int n = n0 + ry * 8 + i;
        const double sn = sqb[n];
        double bestv = INFINITY;
        int besti = 0x7fffffff;
#pragma unroll
        for (int mt = 0; mt < 2; ++mt) {
#pragma unroll
            for (int j = 0; j < 4; ++j) {
                const int m = m0 + mt * 128 + mx * 4 + j;
                double v = sn + sqb[m] - 2.0 * (double)acc[i][mt * 4 + j];
                if (v < 0.0) v = 0.0;                 // match jnp.maximum(d2, 0)
                if (m == n) v = INFINITY;             // mask self-match
                if (v < bestv || (v == bestv && m < besti)) { bestv = v; besti = m; }
            }
        }
        // Reduce across the 32 mx-lanes sharing this row (lane = (ry&1)*32+mx,
        // xor-offsets < 32 stay within the mx field).
#pragma unroll
        for (int off = 1; off < 32; off <<= 1) {
            double ov = __shfl_xor(bestv, off);
            int oi = __shfl_xor(besti, off);
            if (ov < bestv || (ov == bestv && oi < besti)) { bestv = ov; besti = oi; }
        }
        if (mx == 0) {
            size_t p = ((size_t)b * NN + n) * MSPLIT + blockIdx.y;
            pmin[p] = bestv;
            pidx[p] = besti;
        }
    }
}

// ---------------------------------------------------------------------------
// Kernel C: reduce the MSPLIT partials per row -> angle = |n - argmin|.
// ---------------------------------------------------------------------------
__global__ __launch_bounds__(256) void reduce_kernel(const double* __restrict__ pmin,
                                                     const int* __restrict__ pidx,
                                                     int* __restrict__ angle) {
    int t = blockIdx.x * 256 + threadIdx.x;      // b*N + n
    int n = t & (NN - 1);
    double bv = INFINITY;
    int bi = 0x7fffffff;
#pragma unroll
    for (int s = 0; s < MSPLIT; ++s) {
        double v = pmin[(size_t)t * MSPLIT + s];
        int i = pidx[(size_t)t * MSPLIT + s];
        if (v < bv || (v == bv && i < bi)) { bv = v; bi = i; }
    }
    int a = n - bi;
    angle[t] = a < 0 ? -a : a;
}

// ---------------------------------------------------------------------------
// Kernel D: out[b,d,n] = x[b,d,n] + emb[angle[b,n], d].
// Threads over n (coalesced x/out); emb gathers hit L2 (emb = 2 MB).
// ---------------------------------------------------------------------------
__global__ __launch_bounds__(256) void out_kernel(const float* __restrict__ x,
                                                  const float* __restrict__ emb,
                                                  const int* __restrict__ angle,
                                                  float* __restrict__ out) {
    const int b = blockIdx.z;
    const int n = blockIdx.x * 256 + threadIdx.x;
    const int d0 = blockIdx.y * 32;
    const int ang = angle[b * NN + n];
    const float* e = emb + (size_t)ang * DD;
    const size_t base = (size_t)b * DD * NN + n;
#pragma unroll 8
    for (int dd = 0; dd < 32; ++dd) {
        const int d = d0 + dd;
        out[base + (size_t)d * NN] = x[base + (size_t)d * NN] + e[d];
    }
}

extern "C" void kernel_launch(void* const* d_in, const int* in_sizes, int n_in,
                              void* d_out, int out_size, void* d_ws, size_t ws_size,
                              hipStream_t stream) {
    const float* x   = (const float*)d_in[0];   // (B, D, N) f32
    const float* emb = (const float*)d_in[1];   // (N, D)    f32
    float* out = (float*)d_out;

    // Workspace carve-up (total ~1.7 MB)
    char* ws = (char*)d_ws;
    double* sq   = (double*)ws;                                       // B*N doubles   (128 KB)
    double* pmin = (double*)(ws + 131072);                            // B*N*8 doubles (1 MB)
    int*    pidx = (int*)   (ws + 131072 + 1048576);                  // B*N*8 ints    (512 KB)
    int*    angl = (int*)   (ws + 131072 + 1048576 + 524288);         // B*N ints      (64 KB)

    sq_kernel<<<dim3(BB * NN / 256), dim3(256), 0, stream>>>(x, sq);
    argmin_kernel<<<dim3(NN / ROWS, MSPLIT, BB), dim3(256), 0, stream>>>(x, sq, pmin, pidx);
    reduce_kernel<<<dim3(BB * NN / 256), dim3(256), 0, stream>>>(pmin, pidx, angl);
    out_kernel<<<dim3(NN / 256, DD / 32, BB), dim3(256), 0, stream>>>(x, emb, angl, out);
}

// Round 2
// 105.592 us; speedup vs baseline: 2.5301x; 2.5301x over previous
//
#include <hip/hip_runtime.h>
#include <math.h>
#include <float.h>

// Fixed instance: B=8, D=256, N=2048
#define BB 8
#define DDIM 256
#define NN 2048

typedef _Float16 half8 __attribute__((ext_vector_type(8)));
typedef float f32x16 __attribute__((ext_vector_type(16)));
typedef unsigned long long u64;

__device__ __forceinline__ u64 umin64(u64 a, u64 b) { return a < b ? a : b; }
__device__ __forceinline__ u64 umax64(u64 a, u64 b) { return a > b ? a : b; }

// ---------------------------------------------------------------------------
// Pre-kernel: x (B,D,N) f32 -> x_hi (B,N,D) f16 (transpose+convert), fused
// per-(b,n,dtile) partial sum-of-squares in f64.
// Block: (b, ntile of 64 n, dtile of 64 d), 256 threads: r = n-lane (coalesced
// reads over n), c = d-chunk-of-16.
// ---------------------------------------------------------------------------
__global__ __launch_bounds__(256) void pre_kernel(const float* __restrict__ x,
                                                  _Float16* __restrict__ xh,
                                                  double* __restrict__ sqpart) {
    __shared__ double lds[4][64];
    const int bx = blockIdx.x;            // 0..127
    const int b = blockIdx.y;
    const int nt = bx >> 2, dt = bx & 3;
    const int n0 = nt * 64, d0 = dt * 64;
    const int t = threadIdx.x;
    const int r = t & 63, c = t >> 6;
    const int n = n0 + r;

    const float* xp = x + ((size_t)b * DDIM + d0 + c * 16) * NN + n;
    float v[16];
#pragma unroll
    for (int q = 0; q < 16; ++q) v[q] = xp[(size_t)q * NN];

    half8 h0, h1;
    double s = 0.0;
#pragma unroll
    for (int q = 0; q < 8; ++q) { h0[q] = (_Float16)v[q];     s += (double)v[q] * v[q]; }
#pragma unroll
    for (int q = 0; q < 8; ++q) { h1[q] = (_Float16)v[8 + q]; s += (double)v[8 + q] * v[8 + q]; }

    const size_t o = ((size_t)b * NN + n) * DDIM + d0 + c * 16;
    *(half8*)&xh[o]     = h0;
    *(half8*)&xh[o + 8] = h1;

    lds[c][r] = s;
    __syncthreads();
    if (c == 0) {
        double sum = lds[0][r] + lds[1][r] + lds[2][r] + lds[3][r];
        sqpart[((size_t)b * NN + n) * 4 + dt] = sum;
    }
}

// ---------------------------------------------------------------------------
// sq finalize: sum 4 d-tile partials (fixed order, deterministic) -> f64 + f32.
// ---------------------------------------------------------------------------
__global__ __launch_bounds__(256) void sqfin_kernel(const double* __restrict__ sqpart,
                                                    double* __restrict__ sq64,
                                                    float* __restrict__ sqf) {
    const int t = blockIdx.x * 256 + threadIdx.x;   // b*N+n
    double s = sqpart[(size_t)t * 4] + sqpart[(size_t)t * 4 + 1]
             + sqpart[(size_t)t * 4 + 2] + sqpart[(size_t)t * 4 + 3];
    sq64[t] = s;
    sqf[t] = (float)s;
}

// ---------------------------------------------------------------------------
// Gram + per-column top-2 kernel. Block: 128 m-rows x 128 n-cols of one batch.
// 4 waves in 2x2 (wm, wn), each computing 64x64 via 2x2 mfma_f32_32x32x16_f16.
// v = 512 + sq[m] - 2*dot  (sq[n] dropped: constant per column; ordering
// preserved). Key = (f32 bits << 16) | m  -> min-key == (min value, min index)
// exactly (values > 0). Self-match (m==n) skipped. Per-column top2 merged
// across the lane^32 pair, then across the wm pair via LDS; written per mt.
// ---------------------------------------------------------------------------
__global__ __launch_bounds__(256) void gram_topk_kernel(const _Float16* __restrict__ xh,
                                                        const float* __restrict__ sqf,
                                                        u64* __restrict__ gk1,
                                                        u64* __restrict__ gk2) {
    __shared__ _Float16 pa[128 * 40];   // 80B row stride: 64B data + 16B pad
    __shared__ _Float16 pb[128 * 40];
    __shared__ float sqm[128];
    __shared__ u64 mbuf[2][2][32][2];

    const int id = blockIdx.x;
    const int b = id & 7;                 // batch fastest -> XCD pinning
    const int t2 = id >> 3;
    const int mt = t2 & 15, nt = t2 >> 4;
    const int m0 = mt << 7, n0 = nt << 7;
    const int t = threadIdx.x;
    const int l = t & 63;
    const int w = t >> 6;
    const int wm = w >> 1, wn = w & 1;

    const _Float16* xb = xh + (size_t)b * NN * DDIM;
    if (t < 128) sqm[t] = sqf[b * NN + m0 + t];

    f32x16 acc[2][2];
#pragma unroll
    for (int i = 0; i < 2; ++i)
#pragma unroll
        for (int j = 0; j < 2; ++j)
#pragma unroll
            for (int r = 0; r < 16; ++r) acc[i][j][r] = 0.0f;

    const int srow = t & 63;   // staging row within a 64-row half
    const int skc = t >> 6;    // 16B chunk 0..3 within the 64B k-slab

    for (int kt = 0; kt < 8; ++kt) {
        const int dbase = kt * 32;
        __syncthreads();
#pragma unroll
        for (int h = 0; h < 2; ++h) {
            const int rr = h * 64 + srow;
            half8 va = *(const half8*)&xb[(size_t)(m0 + rr) * DDIM + dbase + skc * 8];
            *(half8*)&pa[rr * 40 + skc * 8] = va;
            half8 vb = *(const half8*)&xb[(size_t)(n0 + rr) * DDIM + dbase + skc * 8];
            *(half8*)&pb[rr * 40 + skc * 8] = vb;
        }
        __syncthreads();
#pragma unroll
        for (int ks = 0; ks < 2; ++ks) {
            const int ko = ks * 16 + (l >> 5) * 8;
            half8 a0 = *(const half8*)&pa[(wm * 64 + (l & 31)) * 40 + ko];
            half8 a1 = *(const half8*)&pa[(wm * 64 + 32 + (l & 31)) * 40 + ko];
            half8 b0 = *(const half8*)&pb[(wn * 64 + (l & 31)) * 40 + ko];
            half8 b1 = *(const half8*)&pb[(wn * 64 + 32 + (l & 31)) * 40 + ko];
            acc[0][0] = __builtin_amdgcn_mfma_f32_32x32x16_f16(a0, b0, acc[0][0], 0, 0, 0);
            acc[0][1] = __builtin_amdgcn_mfma_f32_32x32x16_f16(a0, b1, acc[0][1], 0, 0, 0);
            acc[1][0] = __builtin_amdgcn_mfma_f32_32x32x16_f16(a1, b0, acc[1][0], 0, 0, 0);
            acc[1][1] = __builtin_amdgcn_mfma_f32_32x32x16_f16(a1, b1, acc[1][1], 0, 0, 0);
        }
    }

    // Epilogue: per-column top-2 over this block's 128 m-rows.
    u64 K1[2], K2[2];
#pragma unroll
    for (int j = 0; j < 2; ++j) {
        const int n_g = n0 + wn * 64 + j * 32 + (l & 31);
        u64 k1 = ~0ull, k2 = ~0ull;
#pragma unroll
        for (int i = 0; i < 2; ++i) {
#pragma unroll
            for (int r = 0; r < 16; ++r) {
                const int mloc = wm * 64 + i * 32 + (r & 3) + ((r >> 2) << 3) + ((l >> 5) << 2);
                const int m_g = m0 + mloc;
                const float v = 512.0f + sqm[mloc] - 2.0f * acc[i][j][r];
                const u64 key = ((u64)__float_as_uint(v) << 16) | (unsigned)m_g;
                if (m_g != n_g) {
                    if (key < k1) { k2 = k1; k1 = key; }
                    else if (key < k2) { k2 = key; }
                }
            }
        }
        u64 o1 = __shfl_xor(k1, 32);
        u64 o2 = __shfl_xor(k2, 32);
        u64 n1 = umin64(k1, o1);
        u64 n2 = umin64(umax64(k1, o1), umin64(k2, o2));
        K1[j] = n1; K2[j] = n2;
    }

    if (wm == 1 && l < 32) {
#pragma unroll
        for (int j = 0; j < 2; ++j) {
            mbuf[wn][j][l][0] = K1[j];
            mbuf[wn][j][l][1] = K2[j];
        }
    }
    __syncthreads();
    if (wm == 0 && l < 32) {
#pragma unroll
        for (int j = 0; j < 2; ++j) {
            u64 o1 = mbuf[wn][j][l][0];
            u64 o2 = mbuf[wn][j][l][1];
            u64 n1 = umin64(K1[j], o1);
            u64 n2 = umin64(umax64(K1[j], o1), umin64(K2[j], o2));
            const int n_g = n0 + wn * 64 + j * 32 + l;
            const size_t base = ((size_t)(b * NN + n_g) << 4) + mt;
            gk1[base] = n1;
            gk2[base] = n2;
        }
    }
}

// ---------------------------------------------------------------------------
// Reduce: merge 16 m-tile top-2 partials per (b,n); if the gap is within
// MARGIN (f16 noise sigma ~1.3e-2, margin 0.1 ~ 7.7 sigma), re-rank the two
// candidates with exact f64 distances (incl. clamp + index tie-break).
// ---------------------------------------------------------------------------
__global__ __launch_bounds__(256) void reduce_kernel(const u64* __restrict__ gk1,
                                                     const u64* __restrict__ gk2,
                                                     const double* __restrict__ sq64,
                                                     const float* __restrict__ x,
                                                     int* __restrict__ angle) {
    const int tg = blockIdx.x * 256 + threadIdx.x;   // b*N+n
    const int b = tg >> 11, n = tg & (NN - 1);
    u64 k1 = ~0ull, k2 = ~0ull;
#pragma unroll
    for (int s = 0; s < 16; ++s) {
        const u64 a = gk1[((size_t)tg << 4) + s];
        const u64 c = gk2[((size_t)tg << 4) + s];
        const u64 n1 = umin64(k1, a);
        const u64 n2 = umin64(umax64(k1, a), umin64(k2, c));
        k1 = n1; k2 = n2;
    }
    const int i1 = (int)(k1 & 0xffff);
    const int i2 = (int)(k2 & 0xffff);
    const float v1 = __uint_as_float((unsigned)(k1 >> 16));
    const float v2 = __uint_as_float((unsigned)(k2 >> 16));
    int best = i1;
    if (v2 - v1 < 0.1f) {
        const float* xb = x + (size_t)b * DDIM * NN;
        double d1 = 0.0, d2 = 0.0;
        for (int d = 0; d < DDIM; ++d) {
            const double xn = xb[(size_t)d * NN + n];
            d1 += xn * (double)xb[(size_t)d * NN + i1];
            d2 += xn * (double)xb[(size_t)d * NN + i2];
        }
        const double sn = sq64[tg];
        double e1 = sn + sq64[(b << 11) + i1] - 2.0 * d1; if (e1 < 0.0) e1 = 0.0;
        double e2 = sn + sq64[(b << 11) + i2] - 2.0 * d2; if (e2 < 0.0) e2 = 0.0;
        if (e2 < e1 || (e2 == e1 && i2 < i1)) best = i2;
    }
    const int a = n - best;
    angle[tg] = a < 0 ? -a : a;
}

// ---------------------------------------------------------------------------
// Output: out[b,d,n] = x[b,d,n] + emb[angle[b,n], d].
// ---------------------------------------------------------------------------
__global__ __launch_bounds__(256) void out_kernel(const float* __restrict__ x,
                                                  const float* __restrict__ emb,
                                                  const int* __restrict__ angle,
                                                  float* __restrict__ out) {
    const int b = blockIdx.z;
    const int n = blockIdx.x * 256 + threadIdx.x;
    const int d0 = blockIdx.y * 32;
    const int ang = angle[b * NN + n];
    const float* e = emb + (size_t)ang * DDIM;
    const size_t base = (size_t)b * DDIM * NN + n;
#pragma unroll 8
    for (int dd = 0; dd < 32; ++dd) {
        const int d = d0 + dd;
        out[base + (size_t)d * NN] = x[base + (size_t)d * NN] + e[d];
    }
}

extern "C" void kernel_launch(void* const* d_in, const int* in_sizes, int n_in,
                              void* d_out, int out_size, void* d_ws, size_t ws_size,
                              hipStream_t stream) {
    const float* x   = (const float*)d_in[0];   // (B, D, N) f32
    const float* emb = (const float*)d_in[1];   // (N, D)    f32
    float* out = (float*)d_out;

    // Workspace carve-up (~12.8 MB total)
    char* ws = (char*)d_ws;
    _Float16* xh   = (_Float16*)ws;                    //  8,388,608 B
    u64*      gk1  = (u64*)(ws + 8388608);             //  2,097,152 B
    u64*      gk2  = (u64*)(ws + 10485760);            //  2,097,152 B
    double*   sqp  = (double*)(ws + 12582912);         //    524,288 B
    double*   sq64 = (double*)(ws + 13107200);         //    131,072 B
    float*    sqf  = (float*)(ws + 13238272);          //     65,536 B
    int*      angl = (int*)(ws + 13303808);            //     65,536 B

    pre_kernel<<<dim3(128, 8), dim3(256), 0, stream>>>(x, xh, sqp);
    sqfin_kernel<<<dim3(64), dim3(256), 0, stream>>>(sqp, sq64, sqf);
    gram_topk_kernel<<<dim3(2048), dim3(256), 0, stream>>>(xh, sqf, gk1, gk2);
    reduce_kernel<<<dim3(64), dim3(256), 0, stream>>>(gk1, gk2, sq64, x, angl);
    out_kernel<<<dim3(NN / 256, DDIM / 32, BB), dim3(256), 0, stream>>>(x, emb, angl, out);
}

// Round 3
// 88.879 us; speedup vs baseline: 3.0058x; 1.1880x over previous
//
#include <hip/hip_runtime.h>
#include <math.h>
#include <float.h>

// Fixed instance: B=8, D=256, N=2048
#define BB 8
#define DDIM 256
#define NN 2048
#define MSPLIT 8            // 2048 / 256 = 8 m-tiles

typedef _Float16 half8 __attribute__((ext_vector_type(8)));
typedef float f32x16 __attribute__((ext_vector_type(16)));
typedef unsigned long long u64;

__device__ __forceinline__ u64 umin64(u64 a, u64 b) { return a < b ? a : b; }
__device__ __forceinline__ u64 umax64(u64 a, u64 b) { return a > b ? a : b; }

// Async global->LDS, 16B per lane. LDS dest must be wave-uniform base
// (HW writes base + lane*16); global src is per-lane.
__device__ __forceinline__ void gload16(const void* g, void* l) {
    __builtin_amdgcn_global_load_lds((const __attribute__((address_space(1))) void*)g,
                                     (__attribute__((address_space(3))) void*)l,
                                     16, 0, 0);
}

// ---------------------------------------------------------------------------
// Pre-kernel: x (B,D,N) f32 -> xh (B,N,D) f16 (transpose+convert), fused
// per-(b,n,dtile) partial sum-of-squares in f64. (unchanged from R2)
// ---------------------------------------------------------------------------
__global__ __launch_bounds__(256) void pre_kernel(const float* __restrict__ x,
                                                  _Float16* __restrict__ xh,
                                                  double* __restrict__ sqpart) {
    __shared__ double lds[4][64];
    const int bx = blockIdx.x;            // 0..127
    const int b = blockIdx.y;
    const int nt = bx >> 2, dt = bx & 3;
    const int n0 = nt * 64, d0 = dt * 64;
    const int t = threadIdx.x;
    const int r = t & 63, c = t >> 6;
    const int n = n0 + r;

    const float* xp = x + ((size_t)b * DDIM + d0 + c * 16) * NN + n;
    float v[16];
#pragma unroll
    for (int q = 0; q < 16; ++q) v[q] = xp[(size_t)q * NN];

    half8 h0, h1;
    double s = 0.0;
#pragma unroll
    for (int q = 0; q < 8; ++q) { h0[q] = (_Float16)v[q];     s += (double)v[q] * v[q]; }
#pragma unroll
    for (int q = 0; q < 8; ++q) { h1[q] = (_Float16)v[8 + q]; s += (double)v[8 + q] * v[8 + q]; }

    const size_t o = ((size_t)b * NN + n) * DDIM + d0 + c * 16;
    *(half8*)&xh[o]     = h0;
    *(half8*)&xh[o + 8] = h1;

    lds[c][r] = s;
    __syncthreads();
    if (c == 0) {
        double sum = lds[0][r] + lds[1][r] + lds[2][r] + lds[3][r];
        sqpart[((size_t)b * NN + n) * 4 + dt] = sum;
    }
}

__global__ __launch_bounds__(256) void sqfin_kernel(const double* __restrict__ sqpart,
                                                    double* __restrict__ sq64,
                                                    float* __restrict__ sqf) {
    const int t = blockIdx.x * 256 + threadIdx.x;   // b*N+n
    double s = sqpart[(size_t)t * 4] + sqpart[(size_t)t * 4 + 1]
             + sqpart[(size_t)t * 4 + 2] + sqpart[(size_t)t * 4 + 3];
    sq64[t] = s;
    sqf[t] = (float)s;
}

// ---------------------------------------------------------------------------
// Gram + per-column top-2. Block tile 256x256 of one batch, 8 waves (2M x 4N),
// wave tile 128x64 via 4x2 mfma_f32_32x32x16_f16. BK=64 double-buffered in
// 128 KB dynamic LDS, staged with global_load_lds (16B). Panels stored
// [row][64 k] (128 B row stride) with XOR chunk swizzle: LDS chunk c of row r
// holds global k-chunk c^(r&7); src pre-swizzled, reads swizzled (linear dest).
// One barrier per K-tile; prefetch of K-tile t+1 overlaps MFMA on t.
// ---------------------------------------------------------------------------
__global__ __launch_bounds__(512, 2) void gram_topk_kernel(const _Float16* __restrict__ xh,
                                                           const float* __restrict__ sqf,
                                                           u64* __restrict__ gk1,
                                                           u64* __restrict__ gk2) {
    extern __shared__ _Float16 smem[];   // 131072 B: A[2][256][64] | B[2][256][64]

    const int id = blockIdx.x;
    const int b  = id & 7;               // batch fastest -> XCD-pinned panels
    const int mt = (id >> 3) & 7;
    const int nt = id >> 6;
    const int m0 = mt << 8, n0 = nt << 8;
    const int tid = threadIdx.x;
    const int l = tid & 63;
    const int w = tid >> 6;              // wave 0..7
    const int wm = w >> 2, wn = w & 3;   // 2 x 4

    const _Float16* xb = xh + (size_t)b * NN * DDIM;

    f32x16 acc[4][2];
#pragma unroll
    for (int i = 0; i < 4; ++i)
#pragma unroll
        for (int j = 0; j < 2; ++j)
#pragma unroll
            for (int r = 0; r < 16; ++r) acc[i][j][r] = 0.0f;

    // Staging: wave w covers rows [w*32, w*32+32) of both panels, 4 instrs
    // of 8 rows each. Lane l -> row-local l>>3, LDS chunk l&7; global src
    // k-chunk (l&7)^(l>>3) so that LDS chunk c holds k-chunk c^(r&7).
    const int srl  = l >> 3;                  // row within 8-row slab == r&7
    const int sswz = (l & 7) ^ srl;           // pre-swizzled global k-chunk

#define STAGE(kt, bufi)                                                          \
    {                                                                            \
        const int kb_ = (kt) * 64 + sswz * 8;                                    \
        _Float16* abase_ = smem + (bufi) * 16384;                                \
        _Float16* bbase_ = smem + 32768 + (bufi) * 16384;                        \
        _Pragma("unroll")                                                        \
        for (int i8 = 0; i8 < 4; ++i8) {                                         \
            const int r0_ = w * 32 + i8 * 8;                                     \
            gload16(xb + (size_t)(m0 + r0_ + srl) * DDIM + kb_, abase_ + r0_ * 64); \
            gload16(xb + (size_t)(n0 + r0_ + srl) * DDIM + kb_, bbase_ + r0_ * 64); \
        }                                                                        \
    }

    int buf = 0;
    STAGE(0, 0);
    __syncthreads();

#pragma unroll
    for (int kt = 0; kt < 4; ++kt) {
        if (kt < 3) STAGE(kt + 1, buf ^ 1);
        const int boff = buf * 16384;
#pragma unroll
        for (int ks = 0; ks < 4; ++ks) {
            const int ch = 2 * ks + (l >> 5);
            half8 a[4], bv[2];
#pragma unroll
            for (int i = 0; i < 4; ++i) {
                const int lrow = wm * 128 + i * 32 + (l & 31);
                const int chunk = ch ^ (lrow & 7);
                a[i] = *(const half8*)&smem[boff + lrow * 64 + chunk * 8];
            }
#pragma unroll
            for (int j = 0; j < 2; ++j) {
                const int lrow = wn * 64 + j * 32 + (l & 31);
                const int chunk = ch ^ (lrow & 7);
                bv[j] = *(const half8*)&smem[32768 + boff + lrow * 64 + chunk * 8];
            }
#pragma unroll
            for (int i = 0; i < 4; ++i)
#pragma unroll
                for (int j = 0; j < 2; ++j)
                    acc[i][j] = __builtin_amdgcn_mfma_f32_32x32x16_f16(a[i], bv[j], acc[i][j], 0, 0, 0);
        }
        if (kt < 3) { __syncthreads(); buf ^= 1; }
    }
#undef STAGE

    // ---- Epilogue: per-column top-2 over this block's 256 m-rows ----
    __syncthreads();                         // panel reads done; reuse LDS
    float* sqAll = (float*)smem;             // 256 f32 @ [0, 1024)
    u64*   mbuf  = (u64*)((char*)smem + 2048); // 256 cols x 2 u64 @ [2048, 6144)
    if (tid < 256) sqAll[tid] = sqf[b * NN + m0 + tid];
    __syncthreads();

    u64 K1[2], K2[2];
#pragma unroll
    for (int j = 0; j < 2; ++j) {
        const int n_g = n0 + wn * 64 + j * 32 + (l & 31);
        u64 k1 = ~0ull, k2 = ~0ull;
#pragma unroll
        for (int i = 0; i < 4; ++i) {
#pragma unroll
            for (int r = 0; r < 16; ++r) {
                const int mloc = wm * 128 + i * 32 + (r & 3) + ((r >> 2) << 3) + ((l >> 5) << 2);
                const int m_g = m0 + mloc;
                const float v = 512.0f + sqAll[mloc] - 2.0f * acc[i][j][r];
                const u64 key = ((u64)__float_as_uint(v) << 16) | (unsigned)m_g;
                if (m_g != n_g) {
                    if (key < k1) { k2 = k1; k1 = key; }
                    else if (key < k2) { k2 = key; }
                }
            }
        }
        u64 o1 = __shfl_xor(k1, 32);
        u64 o2 = __shfl_xor(k2, 32);
        K1[j] = umin64(k1, o1);
        K2[j] = umin64(umax64(k1, o1), umin64(k2, o2));
    }

    if (wm == 1 && l < 32) {
#pragma unroll
        for (int j = 0; j < 2; ++j) {
            const int c = wn * 64 + j * 32 + l;
            mbuf[c * 2]     = K1[j];
            mbuf[c * 2 + 1] = K2[j];
        }
    }
    __syncthreads();
    if (wm == 0 && l < 32) {
#pragma unroll
        for (int j = 0; j < 2; ++j) {
            const int c = wn * 64 + j * 32 + l;
            const u64 o1 = mbuf[c * 2];
            const u64 o2 = mbuf[c * 2 + 1];
            const u64 n1 = umin64(K1[j], o1);
            const u64 n2 = umin64(umax64(K1[j], o1), umin64(K2[j], o2));
            const size_t base = ((size_t)(b * NN + n0 + c) << 3) + mt;
            gk1[base] = n1;
            gk2[base] = n2;
        }
    }
}

// ---------------------------------------------------------------------------
// Reduce: merge 8 m-tile top-2 partials per (b,n); exact f64 re-rank of the
// two candidates when the gap is within margin (f16 noise sigma ~1.3e-2).
// ---------------------------------------------------------------------------
__global__ __launch_bounds__(256) void reduce_kernel(const u64* __restrict__ gk1,
                                                     const u64* __restrict__ gk2,
                                                     const double* __restrict__ sq64,
                                                     const float* __restrict__ x,
                                                     int* __restrict__ angle) {
    const int tg = blockIdx.x * 256 + threadIdx.x;   // b*N+n
    const int b = tg >> 11, n = tg & (NN - 1);
    u64 k1 = ~0ull, k2 = ~0ull;
#pragma unroll
    for (int s = 0; s < MSPLIT; ++s) {
        const u64 a = gk1[((size_t)tg << 3) + s];
        const u64 c = gk2[((size_t)tg << 3) + s];
        const u64 n1 = umin64(k1, a);
        const u64 n2 = umin64(umax64(k1, a), umin64(k2, c));
        k1 = n1; k2 = n2;
    }
    const int i1 = (int)(k1 & 0xffff);
    const int i2 = (int)(k2 & 0xffff);
    const float v1 = __uint_as_float((unsigned)(k1 >> 16));
    const float v2 = __uint_as_float((unsigned)(k2 >> 16));
    int best = i1;
    if (v2 - v1 < 0.1f) {
        const float* xb = x + (size_t)b * DDIM * NN;
        double d1 = 0.0, d2 = 0.0;
        for (int d = 0; d < DDIM; ++d) {
            const double xn = xb[(size_t)d * NN + n];
            d1 += xn * (double)xb[(size_t)d * NN + i1];
            d2 += xn * (double)xb[(size_t)d * NN + i2];
        }
        const double sn = sq64[tg];
        double e1 = sn + sq64[(b << 11) + i1] - 2.0 * d1; if (e1 < 0.0) e1 = 0.0;
        double e2 = sn + sq64[(b << 11) + i2] - 2.0 * d2; if (e2 < 0.0) e2 = 0.0;
        if (e2 < e1 || (e2 == e1 && i2 < i1)) best = i2;
    }
    const int a = n - best;
    angle[tg] = a < 0 ? -a : a;
}

// ---------------------------------------------------------------------------
// Output: out[b,d,n] = x[b,d,n] + emb[angle[b,n], d].
// ---------------------------------------------------------------------------
__global__ __launch_bounds__(256) void out_kernel(const float* __restrict__ x,
                                                  const float* __restrict__ emb,
                                                  const int* __restrict__ angle,
                                                  float* __restrict__ out) {
    const int b = blockIdx.z;
    const int n = blockIdx.x * 256 + threadIdx.x;
    const int d0 = blockIdx.y * 32;
    const int ang = angle[b * NN + n];
    const float* e = emb + (size_t)ang * DDIM;
    const size_t base = (size_t)b * DDIM * NN + n;
#pragma unroll 8
    for (int dd = 0; dd < 32; ++dd) {
        const int d = d0 + dd;
        out[base + (size_t)d * NN] = x[base + (size_t)d * NN] + e[d];
    }
}

extern "C" void kernel_launch(void* const* d_in, const int* in_sizes, int n_in,
                              void* d_out, int out_size, void* d_ws, size_t ws_size,
                              hipStream_t stream) {
    const float* x   = (const float*)d_in[0];   // (B, D, N) f32
    const float* emb = (const float*)d_in[1];   // (N, D)    f32
    float* out = (float*)d_out;

    // Workspace carve-up (~10.8 MB total)
    char* ws = (char*)d_ws;
    _Float16* xh   = (_Float16*)ws;                    //  8,388,608 B
    u64*      gk1  = (u64*)(ws + 8388608);             //  1,048,576 B
    u64*      gk2  = (u64*)(ws + 9437184);             //  1,048,576 B
    double*   sqp  = (double*)(ws + 10485760);         //    524,288 B
    double*   sq64 = (double*)(ws + 11010048);         //    131,072 B
    float*    sqf  = (float*)(ws + 11141120);          //     65,536 B
    int*      angl = (int*)(ws + 11206656);            //     65,536 B

    // 128 KB dynamic LDS needs the attribute raised (idempotent, host-side).
    hipFuncSetAttribute(reinterpret_cast<const void*>(gram_topk_kernel),
                        hipFuncAttributeMaxDynamicSharedMemorySize, 131072);

    pre_kernel<<<dim3(128, 8), dim3(256), 0, stream>>>(x, xh, sqp);
    sqfin_kernel<<<dim3(64), dim3(256), 0, stream>>>(sqp, sq64, sqf);
    gram_topk_kernel<<<dim3(512), dim3(512), 131072, stream>>>(xh, sqf, gk1, gk2);
    reduce_kernel<<<dim3(64), dim3(256), 0, stream>>>(gk1, gk2, sq64, x, angl);
    out_kernel<<<dim3(NN / 256, DDIM / 32, BB), dim3(256), 0, stream>>>(x, emb, angl, out);
}

// Round 4
// 75.206 us; speedup vs baseline: 3.5523x; 1.1818x over previous
//
#include <hip/hip_runtime.h>
#include <math.h>
#include <float.h>

// Fixed instance: B=8, D=256, N=2048
#define BB 8
#define DDIM 256
#define NN 2048
#define MSPLIT 8            // 2048 / 256 = 8 m-tiles

typedef _Float16 half8 __attribute__((ext_vector_type(8)));
typedef float f32x16 __attribute__((ext_vector_type(16)));
typedef unsigned u32;
typedef unsigned long long u64;

__device__ __forceinline__ u32 umin32(u32 a, u32 b) { return a < b ? a : b; }
__device__ __forceinline__ u32 umax32(u32 a, u32 b) { return a > b ? a : b; }
__device__ __forceinline__ u64 umin64(u64 a, u64 b) { return a < b ? a : b; }
__device__ __forceinline__ u64 umax64(u64 a, u64 b) { return a > b ? a : b; }

// Async global->LDS, 16B per lane. LDS dest is wave-uniform base + lane*16;
// global src is per-lane (so swizzles are applied on the source side).
__device__ __forceinline__ void gload16(const void* g, void* l) {
    __builtin_amdgcn_global_load_lds((const __attribute__((address_space(1))) void*)g,
                                     (__attribute__((address_space(3))) void*)l,
                                     16, 0, 0);
}

// ---------------------------------------------------------------------------
// Pre-kernel: x (B,D,N) f32 -> xh (B,N,D) f16 (transpose+convert) with
// fully-coalesced xh writes (each wave writes 16 rows x 128 B segments),
// fused full-D sum-of-squares in f64 (no separate finalize kernel).
// Grid (32 ntiles, 8 b) x 256 thr; thread owns (c4 = 16-d chunk, r = n-lane).
// ---------------------------------------------------------------------------
__global__ __launch_bounds__(256) void pre_kernel(const float* __restrict__ x,
                                                  _Float16* __restrict__ xh,
                                                  double* __restrict__ sq64,
                                                  float* __restrict__ sqf) {
    __shared__ double lds[4][64];
    const int b = blockIdx.y;
    const int n0 = blockIdx.x * 64;
    const int t = threadIdx.x;
    const int c4 = t & 3;        // which 16-d chunk within a 64-d tile
    const int r = t >> 2;        // n-offset 0..63
    const int n = n0 + r;

    double s = 0.0;
#pragma unroll
    for (int dt = 0; dt < 4; ++dt) {
        const int db = dt * 64 + c4 * 16;
        const float* xp = x + ((size_t)b * DDIM + db) * NN + n;
        float v[16];
#pragma unroll
        for (int q = 0; q < 16; ++q) v[q] = xp[(size_t)q * NN];

        half8 h0, h1;
#pragma unroll
        for (int q = 0; q < 8; ++q) { h0[q] = (_Float16)v[q];     s += (double)v[q] * v[q]; }
#pragma unroll
        for (int q = 0; q < 8; ++q) { h1[q] = (_Float16)v[8 + q]; s += (double)v[8 + q] * v[8 + q]; }

        const size_t o = ((size_t)b * NN + n) * DDIM + db;
        *(half8*)&xh[o]     = h0;
        *(half8*)&xh[o + 8] = h1;
    }

    lds[c4][r] = s;
    __syncthreads();
    if (c4 == 0) {
        const double sum = lds[0][r] + lds[1][r] + lds[2][r] + lds[3][r];
        sq64[b * NN + n] = sum;
        sqf[b * NN + n] = (float)sum;
    }
}

// ---------------------------------------------------------------------------
// Gram + per-column top-2. Block tile 256x256 of one batch, 8 waves (2M x 4N),
// wave tile 128x64 via 4x2 mfma_f32_32x32x16_f16. BK=64 double-buffered in
// 128 KB dynamic LDS, staged with global_load_lds (16B), XOR chunk swizzle
// (source pre-swizzled, reads swizzled, linear LDS dest).
// Epilogue: u32 keys = (f32 bits of v & ~0xff) | mloc (8-bit tile-local m);
// 15 mantissa bits kept (quant step ~0.016 ~= f16 noise). 3 u32 min/max per
// candidate; sq loaded via float4 from LDS (not per-candidate scalar reads).
// ---------------------------------------------------------------------------
__global__ __launch_bounds__(512, 2) void gram_topk_kernel(const _Float16* __restrict__ xh,
                                                           const float* __restrict__ sqf,
                                                           u32* __restrict__ gk1,
                                                           u32* __restrict__ gk2) {
    extern __shared__ _Float16 smem[];   // 131072 B: A[2][256][64] | B[2][256][64]

    const int id = blockIdx.x;
    const int b  = id & 7;               // batch fastest -> XCD-pinned panels
    const int mt = (id >> 3) & 7;
    const int nt = id >> 6;
    const int m0 = mt << 8, n0 = nt << 8;
    const int tid = threadIdx.x;
    const int l = tid & 63;
    const int w = tid >> 6;              // wave 0..7
    const int wm = w >> 2, wn = w & 3;   // 2 x 4

    const _Float16* xb = xh + (size_t)b * NN * DDIM;

    f32x16 acc[4][2];
#pragma unroll
    for (int i = 0; i < 4; ++i)
#pragma unroll
        for (int j = 0; j < 2; ++j)
#pragma unroll
            for (int r = 0; r < 16; ++r) acc[i][j][r] = 0.0f;

    // Staging: wave w covers rows [w*32, w*32+32) of both panels.
    // Lane l -> row-local l>>3, LDS chunk l&7; global k-chunk (l&7)^(l>>3)
    // so LDS chunk c of row r holds global chunk c^(r&7).
    const int srl  = l >> 3;
    const int sswz = (l & 7) ^ srl;

#define STAGE(kt, bufi)                                                          \
    {                                                                            \
        const int kb_ = (kt) * 64 + sswz * 8;                                    \
        _Float16* abase_ = smem + (bufi) * 16384;                                \
        _Float16* bbase_ = smem + 32768 + (bufi) * 16384;                        \
        _Pragma("unroll")                                                        \
        for (int i8 = 0; i8 < 4; ++i8) {                                         \
            const int r0_ = w * 32 + i8 * 8;                                     \
            gload16(xb + (size_t)(m0 + r0_ + srl) * DDIM + kb_, abase_ + r0_ * 64); \
            gload16(xb + (size_t)(n0 + r0_ + srl) * DDIM + kb_, bbase_ + r0_ * 64); \
        }                                                                        \
    }

    int buf = 0;
    STAGE(0, 0);
    __syncthreads();

#pragma unroll
    for (int kt = 0; kt < 4; ++kt) {
        if (kt < 3) STAGE(kt + 1, buf ^ 1);
        const int boff = buf * 16384;
#pragma unroll
        for (int ks = 0; ks < 4; ++ks) {
            const int ch = 2 * ks + (l >> 5);
            half8 a[4], bv[2];
#pragma unroll
            for (int i = 0; i < 4; ++i) {
                const int lrow = wm * 128 + i * 32 + (l & 31);
                const int chunk = ch ^ (lrow & 7);
                a[i] = *(const half8*)&smem[boff + lrow * 64 + chunk * 8];
            }
#pragma unroll
            for (int j = 0; j < 2; ++j) {
                const int lrow = wn * 64 + j * 32 + (l & 31);
                const int chunk = ch ^ (lrow & 7);
                bv[j] = *(const half8*)&smem[32768 + boff + lrow * 64 + chunk * 8];
            }
#pragma unroll
            for (int i = 0; i < 4; ++i)
#pragma unroll
                for (int j = 0; j < 2; ++j)
                    acc[i][j] = __builtin_amdgcn_mfma_f32_32x32x16_f16(a[i], bv[j], acc[i][j], 0, 0, 0);
        }
        if (kt < 3) { __syncthreads(); buf ^= 1; }
    }
#undef STAGE

    // ---- Epilogue: per-column top-2 over this block's 256 m-rows ----
    __syncthreads();                           // all panel reads done; reuse LDS
    float* sqAll = (float*)smem;               // 256 f32 @ [0, 1024)
    u32*   mbuf  = (u32*)((char*)smem + 2048); // 256 cols x 2 u32 @ [2048, 4096)
    if (tid < 256) sqAll[tid] = sqf[b * NN + m0 + tid];
    __syncthreads();

    u32 K1[2], K2[2];
#pragma unroll
    for (int j = 0; j < 2; ++j) {
        const int n_g = n0 + wn * 64 + j * 32 + (l & 31);
        const int delta = n_g - m0;            // self-match when mloc == delta
        u32 k1 = 0xffffffffu, k2 = 0xffffffffu;
#pragma unroll
        for (int i = 0; i < 4; ++i) {
            const int mbase = wm * 128 + i * 32 + ((l >> 5) << 2);
            const float4 s0 = *(const float4*)&sqAll[mbase];
            const float4 s1 = *(const float4*)&sqAll[mbase + 8];
            const float4 s2 = *(const float4*)&sqAll[mbase + 16];
            const float4 s3 = *(const float4*)&sqAll[mbase + 24];
            const float sv[16] = {s0.x, s0.y, s0.z, s0.w, s1.x, s1.y, s1.z, s1.w,
                                  s2.x, s2.y, s2.z, s2.w, s3.x, s3.y, s3.z, s3.w};
#pragma unroll
            for (int r = 0; r < 16; ++r) {
                const int mloc = mbase + (r & 3) + ((r >> 2) << 3);
                const float v = fmaxf(512.0f + sv[r] - 2.0f * acc[i][j][r], 0.0f);
                u32 key = (__float_as_uint(v) & 0xffffff00u) | (u32)mloc;
                key = (mloc == delta) ? 0xffffffffu : key;
                const u32 t = umax32(k1, key);
                k1 = umin32(k1, key);
                k2 = umin32(k2, t);
            }
        }
        const u32 o1 = __shfl_xor(k1, 32);
        const u32 o2 = __shfl_xor(k2, 32);
        K1[j] = umin32(k1, o1);
        K2[j] = umin32(umax32(k1, o1), umin32(k2, o2));
    }

    if (wm == 1 && l < 32) {
#pragma unroll
        for (int j = 0; j < 2; ++j) {
            const int c = wn * 64 + j * 32 + l;
            mbuf[c * 2]     = K1[j];
            mbuf[c * 2 + 1] = K2[j];
        }
    }
    __syncthreads();
    if (wm == 0 && l < 32) {
#pragma unroll
        for (int j = 0; j < 2; ++j) {
            const int c = wn * 64 + j * 32 + l;
            const u32 o1 = mbuf[c * 2];
            const u32 o2 = mbuf[c * 2 + 1];
            const u32 n1 = umin32(K1[j], o1);
            const u32 n2 = umin32(umax32(K1[j], o1), umin32(K2[j], o2));
            const size_t base = ((size_t)(b * NN + n0 + c) << 3) + mt;
            gk1[base] = n1;
            gk2[base] = n2;
        }
    }
}

// ---------------------------------------------------------------------------
// Reduce: expand each slot's u32 key to a u64 (quantized v bits, then GLOBAL
// m = slot*256 + local for exact cross-slot index tie-break), merge top-2
// over 8 slots, then exact f64 re-rank of the two candidates when the
// quantized gap is within margin (f16 noise + quantization, 0.1 ~= 6 sigma).
// ---------------------------------------------------------------------------
__global__ __launch_bounds__(256) void reduce_kernel(const u32* __restrict__ gk1,
                                                     const u32* __restrict__ gk2,
                                                     const double* __restrict__ sq64,
                                                     const float* __restrict__ x,
                                                     int* __restrict__ angle) {
    const int tg = blockIdx.x * 256 + threadIdx.x;   // b*N+n
    const int b = tg >> 11, n = tg & (NN - 1);
    u64 k1 = ~0ull, k2 = ~0ull;
#pragma unroll
    for (int s = 0; s < MSPLIT; ++s) {
        const u32 a = gk1[((size_t)tg << 3) + s];
        const u32 c = gk2[((size_t)tg << 3) + s];
        const u64 ka = ((u64)(a >> 8) << 11) | (u32)((s << 8) | (a & 0xff));
        const u64 kc = ((u64)(c >> 8) << 11) | (u32)((s << 8) | (c & 0xff));
        const u64 n1 = umin64(k1, ka);
        const u64 n2 = umin64(umax64(k1, ka), umin64(k2, kc));
        k1 = n1; k2 = n2;
    }
    const int i1 = (int)(k1 & 0x7ff);
    const int i2 = (int)(k2 & 0x7ff);
    const float v1 = __uint_as_float((u32)(k1 >> 11) << 8);
    const float v2 = __uint_as_float((u32)(k2 >> 11) << 8);
    int best = i1;
    if (v2 - v1 < 0.1f) {
        const float* xb = x + (size_t)b * DDIM * NN;
        double d1 = 0.0, d2 = 0.0;
        for (int d = 0; d < DDIM; ++d) {
            const double xn = xb[(size_t)d * NN + n];
            d1 += xn * (double)xb[(size_t)d * NN + i1];
            d2 += xn * (double)xb[(size_t)d * NN + i2];
        }
        const double sn = sq64[tg];
        double e1 = sn + sq64[(b << 11) + i1] - 2.0 * d1; if (e1 < 0.0) e1 = 0.0;
        double e2 = sn + sq64[(b << 11) + i2] - 2.0 * d2; if (e2 < 0.0) e2 = 0.0;
        if (e2 < e1 || (e2 == e1 && i2 < i1)) best = i2;
    }
    const int a = n - best;
    angle[tg] = a < 0 ? -a : a;
}

// ---------------------------------------------------------------------------
// Output: out[b,d,n] = x[b,d,n] + emb[angle[b,n], d].
// ---------------------------------------------------------------------------
__global__ __launch_bounds__(256) void out_kernel(const float* __restrict__ x,
                                                  const float* __restrict__ emb,
                                                  const int* __restrict__ angle,
                                                  float* __restrict__ out) {
    const int b = blockIdx.z;
    const int n = blockIdx.x * 256 + threadIdx.x;
    const int d0 = blockIdx.y * 32;
    const int ang = angle[b * NN + n];
    const float* e = emb + (size_t)ang * DDIM;
    const size_t base = (size_t)b * DDIM * NN + n;
#pragma unroll 8
    for (int dd = 0; dd < 32; ++dd) {
        const int d = d0 + dd;
        out[base + (size_t)d * NN] = x[base + (size_t)d * NN] + e[d];
    }
}

extern "C" void kernel_launch(void* const* d_in, const int* in_sizes, int n_in,
                              void* d_out, int out_size, void* d_ws, size_t ws_size,
                              hipStream_t stream) {
    const float* x   = (const float*)d_in[0];   // (B, D, N) f32
    const float* emb = (const float*)d_in[1];   // (N, D)    f32
    float* out = (float*)d_out;

    // Workspace carve-up (~9.7 MB total)
    char* ws = (char*)d_ws;
    _Float16* xh   = (_Float16*)ws;                    // 8,388,608 B
    u32*      gk1  = (u32*)(ws + 8388608);             //   524,288 B
    u32*      gk2  = (u32*)(ws + 8912896);             //   524,288 B
    double*   sq64 = (double*)(ws + 9437184);          //   131,072 B
    float*    sqf  = (float*)(ws + 9568256);           //    65,536 B
    int*      angl = (int*)(ws + 9633792);             //    65,536 B

    // 128 KB dynamic LDS needs the attribute raised (host-side, capture-safe).
    hipFuncSetAttribute(reinterpret_cast<const void*>(gram_topk_kernel),
                        hipFuncAttributeMaxDynamicSharedMemorySize, 131072);

    pre_kernel<<<dim3(32, 8), dim3(256), 0, stream>>>(x, xh, sq64, sqf);
    gram_topk_kernel<<<dim3(512), dim3(512), 131072, stream>>>(xh, sqf, gk1, gk2);
    reduce_kernel<<<dim3(64), dim3(256), 0, stream>>>(gk1, gk2, sq64, x, angl);
    out_kernel<<<dim3(NN / 256, DDIM / 32, BB), dim3(256), 0, stream>>>(x, emb, angl, out);
}

// Round 5
// 70.715 us; speedup vs baseline: 3.7779x; 1.0635x over previous
//
#include <hip/hip_runtime.h>
#include <math.h>
#include <float.h>

// Fixed instance: B=8, D=256, N=2048
#define BB 8
#define DDIM 256
#define NN 2048
#define MSPLIT 8            // 2048 / 256 = 8 m-tiles

typedef _Float16 half8 __attribute__((ext_vector_type(8)));
typedef float f32x16 __attribute__((ext_vector_type(16)));
typedef unsigned u32;
typedef unsigned long long u64;

__device__ __forceinline__ u32 umin32(u32 a, u32 b) { return a < b ? a : b; }
__device__ __forceinline__ u32 umax32(u32 a, u32 b) { return a > b ? a : b; }
__device__ __forceinline__ u64 umin64(u64 a, u64 b) { return a < b ? a : b; }
__device__ __forceinline__ u64 umax64(u64 a, u64 b) { return a > b ? a : b; }

// Async global->LDS, 16B per lane. LDS dest is wave-uniform base + lane*16;
// global src is per-lane (so swizzles are applied on the source side).
__device__ __forceinline__ void gload16(const void* g, void* l) {
    __builtin_amdgcn_global_load_lds((const __attribute__((address_space(1))) void*)g,
                                     (__attribute__((address_space(3))) void*)l,
                                     16, 0, 0);
}

// ---------------------------------------------------------------------------
// Pre-kernel: x (B,D,N) f32 -> xh (B,N,D) f16 (transpose+convert), coalesced
// xh writes (128 B row segments), fused full-D sum-of-squares in f64.
// ---------------------------------------------------------------------------
__global__ __launch_bounds__(256) void pre_kernel(const float* __restrict__ x,
                                                  _Float16* __restrict__ xh,
                                                  double* __restrict__ sq64,
                                                  float* __restrict__ sqf) {
    __shared__ double lds[4][64];
    const int b = blockIdx.y;
    const int n0 = blockIdx.x * 64;
    const int t = threadIdx.x;
    const int c4 = t & 3;        // which 16-d chunk within a 64-d tile
    const int r = t >> 2;        // n-offset 0..63
    const int n = n0 + r;

    double s = 0.0;
#pragma unroll
    for (int dt = 0; dt < 4; ++dt) {
        const int db = dt * 64 + c4 * 16;
        const float* xp = x + ((size_t)b * DDIM + db) * NN + n;
        float v[16];
#pragma unroll
        for (int q = 0; q < 16; ++q) v[q] = xp[(size_t)q * NN];

        half8 h0, h1;
#pragma unroll
        for (int q = 0; q < 8; ++q) { h0[q] = (_Float16)v[q];     s += (double)v[q] * v[q]; }
#pragma unroll
        for (int q = 0; q < 8; ++q) { h1[q] = (_Float16)v[8 + q]; s += (double)v[8 + q] * v[8 + q]; }

        const size_t o = ((size_t)b * NN + n) * DDIM + db;
        *(half8*)&xh[o]     = h0;
        *(half8*)&xh[o + 8] = h1;
    }

    lds[c4][r] = s;
    __syncthreads();
    if (c4 == 0) {
        const double sum = lds[0][r] + lds[1][r] + lds[2][r] + lds[3][r];
        sq64[b * NN + n] = sum;
        sqf[b * NN + n] = (float)sum;
    }
}

// ---------------------------------------------------------------------------
// Epilogue scan helper: per-column top-2 insert over this wave's 128 m-rows.
// DIAG: self-match masking needed only when mt == nt (block-uniform).
// Keys: (f32 bits of v & ~0xff) | mloc  (8-bit tile-local m); 15 mantissa
// bits kept (quant step ~0.0156 at v~512).
// ---------------------------------------------------------------------------
template<bool DIAG>
__device__ __forceinline__ void epi_scan(const f32x16 (&acc)[4][2],
                                         const float* __restrict__ sqm_g,
                                         int wm, int l, int delta0,
                                         u32 (&k1a)[2], u32 (&k2a)[2]) {
#pragma unroll
    for (int i = 0; i < 4; ++i) {
        const int mbase = wm * 128 + i * 32 + ((l >> 5) << 2);
        const float4 s0 = *(const float4*)&sqm_g[mbase];
        const float4 s1 = *(const float4*)&sqm_g[mbase + 8];
        const float4 s2 = *(const float4*)&sqm_g[mbase + 16];
        const float4 s3 = *(const float4*)&sqm_g[mbase + 24];
        const float svp[16] = {512.0f + s0.x, 512.0f + s0.y, 512.0f + s0.z, 512.0f + s0.w,
                               512.0f + s1.x, 512.0f + s1.y, 512.0f + s1.z, 512.0f + s1.w,
                               512.0f + s2.x, 512.0f + s2.y, 512.0f + s2.z, 512.0f + s2.w,
                               512.0f + s3.x, 512.0f + s3.y, 512.0f + s3.z, 512.0f + s3.w};
#pragma unroll
        for (int j = 0; j < 2; ++j) {
            const int delta = delta0 + j * 32;
#pragma unroll
            for (int r = 0; r < 16; ++r) {
                const int mloc = mbase + (r & 3) + ((r >> 2) << 3);
                const float v = fmaxf(fmaf(-2.0f, acc[i][j][r], svp[r]), 0.0f);
                u32 key = (__float_as_uint(v) & 0xffffff00u) | (u32)mloc;
                if constexpr (DIAG) key = (mloc == delta) ? 0xffffffffu : key;
                const u32 t = umax32(k1a[j], key);
                k1a[j] = umin32(k1a[j], key);
                k2a[j] = umin32(k2a[j], t);
            }
        }
    }
}

// ---------------------------------------------------------------------------
// Gram + per-column top-2. Block tile 256x256 of one batch, 8 waves (2M x 4N),
// wave tile 128x64 via 4x2 mfma_f32_32x32x16_f16. BK=64 double-buffered in
// 128 KB dynamic LDS, staged with global_load_lds (16B), XOR chunk swizzle
// (source pre-swizzled, reads swizzled, linear LDS dest).
// ---------------------------------------------------------------------------
__global__ __launch_bounds__(512, 2) void gram_topk_kernel(const _Float16* __restrict__ xh,
                                                           const float* __restrict__ sqf,
                                                           u32* __restrict__ gk1,
                                                           u32* __restrict__ gk2) {
    extern __shared__ _Float16 smem[];   // 131072 B: A[2][256][64] | B[2][256][64]

    const int id = blockIdx.x;
    const int b  = id & 7;               // batch fastest -> XCD-pinned panels
    const int mt = (id >> 3) & 7;
    const int nt = id >> 6;
    const int m0 = mt << 8, n0 = nt << 8;
    const int tid = threadIdx.x;
    const int l = tid & 63;
    const int w = tid >> 6;              // wave 0..7
    const int wm = w >> 2, wn = w & 3;   // 2 x 4

    const _Float16* xb = xh + (size_t)b * NN * DDIM;

    f32x16 acc[4][2];
#pragma unroll
    for (int i = 0; i < 4; ++i)
#pragma unroll
        for (int j = 0; j < 2; ++j)
#pragma unroll
            for (int r = 0; r < 16; ++r) acc[i][j][r] = 0.0f;

    // Staging: wave w covers rows [w*32, w*32+32) of both panels.
    // Lane l -> row-local l>>3, LDS chunk l&7; global k-chunk (l&7)^(l>>3)
    // so LDS chunk c of row r holds global chunk c^(r&7).
    const int srl  = l >> 3;
    const int sswz = (l & 7) ^ srl;

#define STAGE(kt, bufi)                                                          \
    {                                                                            \
        const int kb_ = (kt) * 64 + sswz * 8;                                    \
        _Float16* abase_ = smem + (bufi) * 16384;                                \
        _Float16* bbase_ = smem + 32768 + (bufi) * 16384;                        \
        _Pragma("unroll")                                                        \
        for (int i8 = 0; i8 < 4; ++i8) {                                         \
            const int r0_ = w * 32 + i8 * 8;                                     \
            gload16(xb + (size_t)(m0 + r0_ + srl) * DDIM + kb_, abase_ + r0_ * 64); \
            gload16(xb + (size_t)(n0 + r0_ + srl) * DDIM + kb_, bbase_ + r0_ * 64); \
        }                                                                        \
    }

    int buf = 0;
    STAGE(0, 0);
    __syncthreads();

#pragma unroll
    for (int kt = 0; kt < 4; ++kt) {
        if (kt < 3) STAGE(kt + 1, buf ^ 1);
        const int boff = buf * 16384;
#pragma unroll
        for (int ks = 0; ks < 4; ++ks) {
            const int ch = 2 * ks + (l >> 5);
            half8 a[4], bv[2];
#pragma unroll
            for (int i = 0; i < 4; ++i) {
                const int lrow = wm * 128 + i * 32 + (l & 31);
                const int chunk = ch ^ (lrow & 7);
                a[i] = *(const half8*)&smem[boff + lrow * 64 + chunk * 8];
            }
#pragma unroll
            for (int j = 0; j < 2; ++j) {
                const int lrow = wn * 64 + j * 32 + (l & 31);
                const int chunk = ch ^ (lrow & 7);
                bv[j] = *(const half8*)&smem[32768 + boff + lrow * 64 + chunk * 8];
            }
#pragma unroll
            for (int i = 0; i < 4; ++i)
#pragma unroll
                for (int j = 0; j < 2; ++j)
                    acc[i][j] = __builtin_amdgcn_mfma_f32_32x32x16_f16(a[i], bv[j], acc[i][j], 0, 0, 0);
        }
        if (kt < 3) { __syncthreads(); buf ^= 1; }
    }
#undef STAGE

    // ---- Epilogue: per-column top-2 over this block's 256 m-rows ----
    __syncthreads();                           // all panel reads done; reuse LDS
    u32* mbuf = (u32*)smem;                    // 256 cols x 2 u32

    const float* sqm_g = sqf + b * NN + m0;    // L2-resident, float4 loads
    u32 k1a[2] = {0xffffffffu, 0xffffffffu};
    u32 k2a[2] = {0xffffffffu, 0xffffffffu};
    const int delta0 = n0 + wn * 64 + (l & 31) - m0;   // n_g - m0 for j=0
    if (mt == nt) epi_scan<true >(acc, sqm_g, wm, l, delta0, k1a, k2a);
    else          epi_scan<false>(acc, sqm_g, wm, l, delta0, k1a, k2a);

    u32 K1[2], K2[2];
#pragma unroll
    for (int j = 0; j < 2; ++j) {
        const u32 o1 = __shfl_xor(k1a[j], 32);
        const u32 o2 = __shfl_xor(k2a[j], 32);
        K1[j] = umin32(k1a[j], o1);
        K2[j] = umin32(umax32(k1a[j], o1), umin32(k2a[j], o2));
    }

    if (wm == 1 && l < 32) {
#pragma unroll
        for (int j = 0; j < 2; ++j) {
            const int c = wn * 64 + j * 32 + l;
            mbuf[c * 2]     = K1[j];
            mbuf[c * 2 + 1] = K2[j];
        }
    }
    __syncthreads();
    if (wm == 0 && l < 32) {
#pragma unroll
        for (int j = 0; j < 2; ++j) {
            const int c = wn * 64 + j * 32 + l;
            const u32 o1 = mbuf[c * 2];
            const u32 o2 = mbuf[c * 2 + 1];
            const u32 n1 = umin32(K1[j], o1);
            const u32 n2 = umin32(umax32(K1[j], o1), umin32(K2[j], o2));
            const size_t base = ((size_t)(b * NN + n0 + c) << 3) + mt;
            gk1[base] = n1;
            gk2[base] = n2;
        }
    }
}

// ---------------------------------------------------------------------------
// Reduce: merge 8 m-tile top-2 partials per (b,n) (u64-expanded for exact
// cross-slot index tie-break); write provisional angle from approx-best; flag
// ambiguous rows (quantized gap < 0.25 ~ 5.5 sigma of f16+quant noise) into a
// compact list for the dense fix kernel.
// ---------------------------------------------------------------------------
__global__ __launch_bounds__(256) void reduce_kernel(const u32* __restrict__ gk1,
                                                     const u32* __restrict__ gk2,
                                                     int* __restrict__ angle,
                                                     int* __restrict__ cnt,
                                                     int4* __restrict__ list) {
    const int tg = blockIdx.x * 256 + threadIdx.x;   // b*N+n
    const int n = tg & (NN - 1);
    u64 k1 = ~0ull, k2 = ~0ull;
#pragma unroll
    for (int s = 0; s < MSPLIT; ++s) {
        const u32 a = gk1[((size_t)tg << 3) + s];
        const u32 c = gk2[((size_t)tg << 3) + s];
        const u64 ka = ((u64)(a >> 8) << 11) | (u32)((s << 8) | (a & 0xff));
        const u64 kc = ((u64)(c >> 8) << 11) | (u32)((s << 8) | (c & 0xff));
        const u64 n1 = umin64(k1, ka);
        const u64 n2 = umin64(umax64(k1, ka), umin64(k2, kc));
        k1 = n1; k2 = n2;
    }
    const int i1 = (int)(k1 & 0x7ff);
    const int i2 = (int)(k2 & 0x7ff);
    const float v1 = __uint_as_float((u32)(k1 >> 11) << 8);
    const float v2 = __uint_as_float((u32)(k2 >> 11) << 8);
    if (v2 - v1 < 0.25f) {
        const int s = atomicAdd(cnt, 1);
        list[s] = make_int4(tg, i1, i2, 0);
    }
    const int a = n - i1;
    angle[tg] = a < 0 ? -a : a;
}

// ---------------------------------------------------------------------------
// Fix: exact f64 re-rank of flagged rows. One wave per row; 64 lanes x 4 d
// each, f64 shuffle reduction; matches np clamp + first-index tie-break.
// ---------------------------------------------------------------------------
__global__ __launch_bounds__(256) void fix_kernel(const int* __restrict__ cnt,
                                                  const int4* __restrict__ list,
                                                  const double* __restrict__ sq64,
                                                  const float* __restrict__ x,
                                                  int* __restrict__ angle) {
    const int c = *cnt;
    const int wid = blockIdx.x * 4 + (threadIdx.x >> 6);
    const int lane = threadIdx.x & 63;
    const int nw = gridDim.x * 4;
    for (int it = wid; it < c; it += nw) {
        const int4 e = list[it];
        const int tg = e.x, i1 = e.y, i2 = e.z;
        const int b = tg >> 11, n = tg & (NN - 1);
        const float* xb = x + (size_t)b * DDIM * NN;
        double d1 = 0.0, d2 = 0.0;
#pragma unroll
        for (int q = 0; q < 4; ++q) {
            const int d = lane * 4 + q;
            const double xn = xb[(size_t)d * NN + n];
            d1 += xn * (double)xb[(size_t)d * NN + i1];
            d2 += xn * (double)xb[(size_t)d * NN + i2];
        }
#pragma unroll
        for (int off = 32; off; off >>= 1) {
            d1 += __shfl_down(d1, off);
            d2 += __shfl_down(d2, off);
        }
        if (lane == 0) {
            const double sn = sq64[tg];
            double e1 = sn + sq64[(b << 11) + i1] - 2.0 * d1; if (e1 < 0.0) e1 = 0.0;
            double e2 = sn + sq64[(b << 11) + i2] - 2.0 * d2; if (e2 < 0.0) e2 = 0.0;
            const int best = (e2 < e1 || (e2 == e1 && i2 < i1)) ? i2 : i1;
            const int a = n - best;
            angle[tg] = a < 0 ? -a : a;
        }
    }
}

// ---------------------------------------------------------------------------
// Output: out[b,d,n] = x[b,d,n] + emb[angle[b,n], d]; float4 over n.
// ---------------------------------------------------------------------------
__global__ __launch_bounds__(256) void out_kernel(const float* __restrict__ x,
                                                  const float* __restrict__ emb,
                                                  const int* __restrict__ angle,
                                                  float* __restrict__ out) {
    const int b = blockIdx.z;
    const int n = (blockIdx.x * 256 + threadIdx.x) * 4;
    const int d0 = blockIdx.y * 16;
    const int4 ang4 = *(const int4*)&angle[b * NN + n];
    const float* e0 = emb + (size_t)ang4.x * DDIM;
    const float* e1 = emb + (size_t)ang4.y * DDIM;
    const float* e2 = emb + (size_t)ang4.z * DDIM;
    const float* e3 = emb + (size_t)ang4.w * DDIM;
    const size_t base = (size_t)b * DDIM * NN + n;
#pragma unroll 8
    for (int dd = 0; dd < 16; ++dd) {
        const int d = d0 + dd;
        const float4 xv = *(const float4*)&x[base + (size_t)d * NN];
        float4 ov;
        ov.x = xv.x + e0[d];
        ov.y = xv.y + e1[d];
        ov.z = xv.z + e2[d];
        ov.w = xv.w + e3[d];
        *(float4*)&out[base + (size_t)d * NN] = ov;
    }
}

extern "C" void kernel_launch(void* const* d_in, const int* in_sizes, int n_in,
                              void* d_out, int out_size, void* d_ws, size_t ws_size,
                              hipStream_t stream) {
    const float* x   = (const float*)d_in[0];   // (B, D, N) f32
    const float* emb = (const float*)d_in[1];   // (N, D)    f32
    float* out = (float*)d_out;

    // Workspace carve-up (~10 MB total)
    char* ws = (char*)d_ws;
    _Float16* xh   = (_Float16*)ws;                    // 8,388,608 B
    u32*      gk1  = (u32*)(ws + 8388608);             //   524,288 B
    u32*      gk2  = (u32*)(ws + 8912896);             //   524,288 B
    double*   sq64 = (double*)(ws + 9437184);          //   131,072 B
    float*    sqf  = (float*)(ws + 9568256);           //    65,536 B
    int*      angl = (int*)(ws + 9633792);             //    65,536 B
    int*      cnt  = (int*)(ws + 9699328);             //       256 B (padded)
    int4*     list = (int4*)(ws + 9699584);            //   262,144 B

    // 128 KB dynamic LDS needs the attribute raised (host-side, capture-safe).
    hipFuncSetAttribute(reinterpret_cast<const void*>(gram_topk_kernel),
                        hipFuncAttributeMaxDynamicSharedMemorySize, 131072);

    hipMemsetAsync(cnt, 0, 4, stream);
    pre_kernel<<<dim3(32, 8), dim3(256), 0, stream>>>(x, xh, sq64, sqf);
    gram_topk_kernel<<<dim3(512), dim3(512), 131072, stream>>>(xh, sqf, gk1, gk2);
    reduce_kernel<<<dim3(64), dim3(256), 0, stream>>>(gk1, gk2, angl, cnt, list);
    fix_kernel<<<dim3(64), dim3(256), 0, stream>>>(cnt, list, sq64, x, angl);
    out_kernel<<<dim3(2, 16, 8), dim3(256), 0, stream>>>(x, emb, angl, out);
}

// Round 6
// 48.169 us; speedup vs baseline: 5.5463x; 1.4681x over previous
//
#include <hip/hip_runtime.h>
#include <math.h>
#include <float.h>

// Fixed instance: B=8, D=256, N=2048
#define BB 8
#define DDIM 256
#define NN 2048
#define MSPLIT 8            // 2048 / 256 = 8 m-tiles

typedef _Float16 half8 __attribute__((ext_vector_type(8)));
typedef float f32x16 __attribute__((ext_vector_type(16)));
typedef unsigned u32;
typedef unsigned long long u64;

__device__ __forceinline__ u32 umin32(u32 a, u32 b) { return a < b ? a : b; }
__device__ __forceinline__ u32 umax32(u32 a, u32 b) { return a > b ? a : b; }
__device__ __forceinline__ u64 umin64(u64 a, u64 b) { return a < b ? a : b; }
__device__ __forceinline__ u64 umax64(u64 a, u64 b) { return a > b ? a : b; }

// Async global->LDS, 16B per lane. LDS dest is wave-uniform base + lane*16;
// global src is per-lane (so swizzles are applied on the source side).
__device__ __forceinline__ void gload16(const void* g, void* l) {
    __builtin_amdgcn_global_load_lds((const __attribute__((address_space(1))) void*)g,
                                     (__attribute__((address_space(3))) void*)l,
                                     16, 0, 0);
}

// ---------------------------------------------------------------------------
// Pre-kernel: x (B,D,N) f32 -> xh (B,N,D) f16 (transpose+convert), coalesced
// xh writes (128 B row segments), fused full-D sum-of-squares in f64.
// ---------------------------------------------------------------------------
__global__ __launch_bounds__(256) void pre_kernel(const float* __restrict__ x,
                                                  _Float16* __restrict__ xh,
                                                  double* __restrict__ sq64,
                                                  float* __restrict__ sqf) {
    __shared__ double lds[4][64];
    const int b = blockIdx.y;
    const int n0 = blockIdx.x * 64;
    const int t = threadIdx.x;
    const int c4 = t & 3;        // which 16-d chunk within a 64-d tile
    const int r = t >> 2;        // n-offset 0..63
    const int n = n0 + r;

    double s = 0.0;
#pragma unroll
    for (int dt = 0; dt < 4; ++dt) {
        const int db = dt * 64 + c4 * 16;
        const float* xp = x + ((size_t)b * DDIM + db) * NN + n;
        float v[16];
#pragma unroll
        for (int q = 0; q < 16; ++q) v[q] = xp[(size_t)q * NN];

        half8 h0, h1;
#pragma unroll
        for (int q = 0; q < 8; ++q) { h0[q] = (_Float16)v[q];     s += (double)v[q] * v[q]; }
#pragma unroll
        for (int q = 0; q < 8; ++q) { h1[q] = (_Float16)v[8 + q]; s += (double)v[8 + q] * v[8 + q]; }

        const size_t o = ((size_t)b * NN + n) * DDIM + db;
        *(half8*)&xh[o]     = h0;
        *(half8*)&xh[o + 8] = h1;
    }

    lds[c4][r] = s;
    __syncthreads();
    if (c4 == 0) {
        const double sum = lds[0][r] + lds[1][r] + lds[2][r] + lds[3][r];
        sq64[b * NN + n] = sum;
        sqf[b * NN + n] = (float)sum;
    }
}

// ---------------------------------------------------------------------------
// Epilogue scan helper: per-column top-2 insert over this wave's 128 m-rows.
// DIAG: self-match masking needed only when mt == nt (block-uniform).
// Keys: (f32 bits of v & ~0xff) | mloc  (8-bit tile-local m); 15 mantissa
// bits kept (quant step ~0.0156 at v~512).
// ---------------------------------------------------------------------------
template<bool DIAG>
__device__ __forceinline__ void epi_scan(const f32x16 (&acc)[4][2],
                                         const float* __restrict__ sqm_g,
                                         int wm, int l, int delta0,
                                         u32 (&k1a)[2], u32 (&k2a)[2]) {
#pragma unroll
    for (int i = 0; i < 4; ++i) {
        const int mbase = wm * 128 + i * 32 + ((l >> 5) << 2);
        const float4 s0 = *(const float4*)&sqm_g[mbase];
        const float4 s1 = *(const float4*)&sqm_g[mbase + 8];
        const float4 s2 = *(const float4*)&sqm_g[mbase + 16];
        const float4 s3 = *(const float4*)&sqm_g[mbase + 24];
        const float svp[16] = {512.0f + s0.x, 512.0f + s0.y, 512.0f + s0.z, 512.0f + s0.w,
                               512.0f + s1.x, 512.0f + s1.y, 512.0f + s1.z, 512.0f + s1.w,
                               512.0f + s2.x, 512.0f + s2.y, 512.0f + s2.z, 512.0f + s2.w,
                               512.0f + s3.x, 512.0f + s3.y, 512.0f + s3.z, 512.0f + s3.w};
#pragma unroll
        for (int j = 0; j < 2; ++j) {
            const int delta = delta0 + j * 32;
#pragma unroll
            for (int r = 0; r < 16; ++r) {
                const int mloc = mbase + (r & 3) + ((r >> 2) << 3);
                const float v = fmaxf(fmaf(-2.0f, acc[i][j][r], svp[r]), 0.0f);
                u32 key = (__float_as_uint(v) & 0xffffff00u) | (u32)mloc;
                if constexpr (DIAG) key = (mloc == delta) ? 0xffffffffu : key;
                const u32 t = umax32(k1a[j], key);
                k1a[j] = umin32(k1a[j], key);
                k2a[j] = umin32(k2a[j], t);
            }
        }
    }
}

// ---------------------------------------------------------------------------
// Gram + per-column top-2. Block tile 256x256 of one batch, 8 waves (2M x 4N),
// wave tile 128x64 via 4x2 mfma_f32_32x32x16_f16. BK=64 double-buffered in
// 128 KB dynamic LDS, staged with global_load_lds (16B), XOR chunk swizzle
// (source pre-swizzled, reads swizzled, linear LDS dest).
// ---------------------------------------------------------------------------
__global__ __launch_bounds__(512, 2) void gram_topk_kernel(const _Float16* __restrict__ xh,
                                                           const float* __restrict__ sqf,
                                                           u32* __restrict__ gk1,
                                                           u32* __restrict__ gk2) {
    extern __shared__ _Float16 smem[];   // 131072 B: A[2][256][64] | B[2][256][64]

    const int id = blockIdx.x;
    const int b  = id & 7;               // batch fastest -> XCD-pinned panels
    const int mt = (id >> 3) & 7;
    const int nt = id >> 6;
    const int m0 = mt << 8, n0 = nt << 8;
    const int tid = threadIdx.x;
    const int l = tid & 63;
    const int w = tid >> 6;              // wave 0..7
    const int wm = w >> 2, wn = w & 3;   // 2 x 4

    const _Float16* xb = xh + (size_t)b * NN * DDIM;

    f32x16 acc[4][2];
#pragma unroll
    for (int i = 0; i < 4; ++i)
#pragma unroll
        for (int j = 0; j < 2; ++j)
#pragma unroll
            for (int r = 0; r < 16; ++r) acc[i][j][r] = 0.0f;

    // Staging: wave w covers rows [w*32, w*32+32) of both panels.
    // Lane l -> row-local l>>3, LDS chunk l&7; global k-chunk (l&7)^(l>>3)
    // so LDS chunk c of row r holds global chunk c^(r&7).
    const int srl  = l >> 3;
    const int sswz = (l & 7) ^ srl;

#define STAGE(kt, bufi)                                                          \
    {                                                                            \
        const int kb_ = (kt) * 64 + sswz * 8;                                    \
        _Float16* abase_ = smem + (bufi) * 16384;                                \
        _Float16* bbase_ = smem + 32768 + (bufi) * 16384;                        \
        _Pragma("unroll")                                                        \
        for (int i8 = 0; i8 < 4; ++i8) {                                         \
            const int r0_ = w * 32 + i8 * 8;                                     \
            gload16(xb + (size_t)(m0 + r0_ + srl) * DDIM + kb_, abase_ + r0_ * 64); \
            gload16(xb + (size_t)(n0 + r0_ + srl) * DDIM + kb_, bbase_ + r0_ * 64); \
        }                                                                        \
    }

    int buf = 0;
    STAGE(0, 0);
    __syncthreads();

#pragma unroll
    for (int kt = 0; kt < 4; ++kt) {
        if (kt < 3) STAGE(kt + 1, buf ^ 1);
        const int boff = buf * 16384;
#pragma unroll
        for (int ks = 0; ks < 4; ++ks) {
            const int ch = 2 * ks + (l >> 5);
            half8 a[4], bv[2];
#pragma unroll
            for (int i = 0; i < 4; ++i) {
                const int lrow = wm * 128 + i * 32 + (l & 31);
                const int chunk = ch ^ (lrow & 7);
                a[i] = *(const half8*)&smem[boff + lrow * 64 + chunk * 8];
            }
#pragma unroll
            for (int j = 0; j < 2; ++j) {
                const int lrow = wn * 64 + j * 32 + (l & 31);
                const int chunk = ch ^ (lrow & 7);
                bv[j] = *(const half8*)&smem[32768 + boff + lrow * 64 + chunk * 8];
            }
#pragma unroll
            for (int i = 0; i < 4; ++i)
#pragma unroll
                for (int j = 0; j < 2; ++j)
                    acc[i][j] = __builtin_amdgcn_mfma_f32_32x32x16_f16(a[i], bv[j], acc[i][j], 0, 0, 0);
        }
        if (kt < 3) { __syncthreads(); buf ^= 1; }
    }
#undef STAGE

    // ---- Epilogue: per-column top-2 over this block's 256 m-rows ----
    __syncthreads();                           // all panel reads done; reuse LDS
    u32* mbuf = (u32*)smem;                    // 256 cols x 2 u32

    const float* sqm_g = sqf + b * NN + m0;    // L2-resident, float4 loads
    u32 k1a[2] = {0xffffffffu, 0xffffffffu};
    u32 k2a[2] = {0xffffffffu, 0xffffffffu};
    const int delta0 = n0 + wn * 64 + (l & 31) - m0;   // n_g - m0 for j=0
    if (mt == nt) epi_scan<true >(acc, sqm_g, wm, l, delta0, k1a, k2a);
    else          epi_scan<false>(acc, sqm_g, wm, l, delta0, k1a, k2a);

    u32 K1[2], K2[2];
#pragma unroll
    for (int j = 0; j < 2; ++j) {
        const u32 o1 = __shfl_xor(k1a[j], 32);
        const u32 o2 = __shfl_xor(k2a[j], 32);
        K1[j] = umin32(k1a[j], o1);
        K2[j] = umin32(umax32(k1a[j], o1), umin32(k2a[j], o2));
    }

    if (wm == 1 && l < 32) {
#pragma unroll
        for (int j = 0; j < 2; ++j) {
            const int c = wn * 64 + j * 32 + l;
            mbuf[c * 2]     = K1[j];
            mbuf[c * 2 + 1] = K2[j];
        }
    }
    __syncthreads();
    if (wm == 0 && l < 32) {
#pragma unroll
        for (int j = 0; j < 2; ++j) {
            const int c = wn * 64 + j * 32 + l;
            const u32 o1 = mbuf[c * 2];
            const u32 o2 = mbuf[c * 2 + 1];
            const u32 n1 = umin32(K1[j], o1);
            const u32 n2 = umin32(umax32(K1[j], o1), umin32(K2[j], o2));
            const size_t base = ((size_t)(b * NN + n0 + c) << 3) + mt;
            gk1[base] = n1;
            gk2[base] = n2;
        }
    }
}

// ---------------------------------------------------------------------------
// Fused tail: per (b, 64-n chunk) block (256 blocks, 1/CU):
//   1) merge 8 top-2 slots per row (u64 keys, exact order) -> approx angle
//   2) flag ambiguous rows (quantized gap < 0.25 ~ 5.5 sigma), re-rank them
//      in-block with 64-lane f64 dots (np clamp + first-index tie-break)
//   3) stage the 64 needed emb rows into LDS **coalesced** (1 wave = 1 row),
//      then out[b,d,n] = x[b,d,n] + embs[n][d] with float4 x/out over n.
// LDS emb stride 257 floats: out-phase read bank = (4*(t&15)+j+(t>>4))%32,
// exact 2-way across 64 lanes = conflict-free.
// ---------------------------------------------------------------------------
__global__ __launch_bounds__(256) void tail_kernel(const u32* __restrict__ gk1,
                                                   const u32* __restrict__ gk2,
                                                   const double* __restrict__ sq64,
                                                   const float* __restrict__ x,
                                                   const float* __restrict__ emb,
                                                   float* __restrict__ out) {
    __shared__ float embs[64][257];
    __shared__ int   angs[64];
    __shared__ int   flist[64][3];
    __shared__ int   fcnt;

    const int b  = blockIdx.y;
    const int n0 = blockIdx.x * 64;
    const int t  = threadIdx.x;
    const int w  = t >> 6, l = t & 63;

    if (t == 0) fcnt = 0;
    __syncthreads();

    // ---- 1) per-row slot merge (threads 0..63, one row each) ----
    if (t < 64) {
        const int n = n0 + t;
        const int tg = (b << 11) + n;
        const uint4 a0 = *(const uint4*)&gk1[(size_t)tg << 3];
        const uint4 a1 = *(const uint4*)&gk1[((size_t)tg << 3) + 4];
        const uint4 c0 = *(const uint4*)&gk2[(size_t)tg << 3];
        const uint4 c1 = *(const uint4*)&gk2[((size_t)tg << 3) + 4];
        const u32 ga[8] = {a0.x, a0.y, a0.z, a0.w, a1.x, a1.y, a1.z, a1.w};
        const u32 gc[8] = {c0.x, c0.y, c0.z, c0.w, c1.x, c1.y, c1.z, c1.w};
        u64 k1 = ~0ull, k2 = ~0ull;
#pragma unroll
        for (int s = 0; s < MSPLIT; ++s) {
            const u64 ka = ((u64)(ga[s] >> 8) << 11) | (u32)((s << 8) | (ga[s] & 0xff));
            const u64 kc = ((u64)(gc[s] >> 8) << 11) | (u32)((s << 8) | (gc[s] & 0xff));
            const u64 n1 = umin64(k1, ka);
            const u64 n2 = umin64(umax64(k1, ka), umin64(k2, kc));
            k1 = n1; k2 = n2;
        }
        const int i1 = (int)(k1 & 0x7ff);
        const int i2 = (int)(k2 & 0x7ff);
        const float v1 = __uint_as_float((u32)(k1 >> 11) << 8);
        const float v2 = __uint_as_float((u32)(k2 >> 11) << 8);
        const int a = n - i1;
        angs[t] = a < 0 ? -a : a;
        if (v2 - v1 < 0.25f) {
            const int s = atomicAdd(&fcnt, 1);   // LDS atomic; <= 64 structurally
            flist[s][0] = t; flist[s][1] = i1; flist[s][2] = i2;
        }
    }
    __syncthreads();

    // ---- 2) exact f64 re-rank of flagged rows (one wave per row) ----
    const int nf = fcnt;
    const float* xb = x + (size_t)b * DDIM * NN;
    for (int it = w; it < nf; it += 4) {
        const int rl = flist[it][0], i1 = flist[it][1], i2 = flist[it][2];
        const int n = n0 + rl;
        double d1 = 0.0, d2 = 0.0;
#pragma unroll
        for (int q = 0; q < 4; ++q) {
            const int d = l * 4 + q;
            const double xn = xb[(size_t)d * NN + n];
            d1 += xn * (double)xb[(size_t)d * NN + i1];
            d2 += xn * (double)xb[(size_t)d * NN + i2];
        }
#pragma unroll
        for (int off = 32; off; off >>= 1) {
            d1 += __shfl_down(d1, off);
            d2 += __shfl_down(d2, off);
        }
        if (l == 0) {
            const double sn = sq64[(b << 11) + n];
            double e1 = sn + sq64[(b << 11) + i1] - 2.0 * d1; if (e1 < 0.0) e1 = 0.0;
            double e2 = sn + sq64[(b << 11) + i2] - 2.0 * d2; if (e2 < 0.0) e2 = 0.0;
            const int best = (e2 < e1 || (e2 == e1 && i2 < i1)) ? i2 : i1;
            const int a = n - best;
            angs[rl] = a < 0 ? -a : a;
        }
    }
    __syncthreads();

    // ---- 3a) stage emb rows coalesced: wave w stages rows w, w+4, ... ----
    for (int rr = w; rr < 64; rr += 4) {
        const int ang = angs[rr];
        const float4 ev = *(const float4*)&emb[(size_t)ang * DDIM + l * 4];
        embs[rr][l * 4]     = ev.x;
        embs[rr][l * 4 + 1] = ev.y;
        embs[rr][l * 4 + 2] = ev.z;
        embs[rr][l * 4 + 3] = ev.w;
    }
    __syncthreads();

    // ---- 3b) output: thread (d-row = t>>4, n-group = t&15), 16 d-iters ----
    const int ng = (t & 15) * 4;
    const int dr = t >> 4;
#pragma unroll
    for (int it = 0; it < 16; ++it) {
        const int d = it * 16 + dr;
        const size_t o = ((size_t)b * DDIM + d) * NN + n0 + ng;
        const float4 xv = *(const float4*)&x[o];
        float4 ov;
        ov.x = xv.x + embs[ng][d];
        ov.y = xv.y + embs[ng + 1][d];
        ov.z = xv.z + embs[ng + 2][d];
        ov.w = xv.w + embs[ng + 3][d];
        *(float4*)&out[o] = ov;
    }
}

extern "C" void kernel_launch(void* const* d_in, const int* in_sizes, int n_in,
                              void* d_out, int out_size, void* d_ws, size_t ws_size,
                              hipStream_t stream) {
    const float* x   = (const float*)d_in[0];   // (B, D, N) f32
    const float* emb = (const float*)d_in[1];   // (N, D)    f32
    float* out = (float*)d_out;

    // Workspace carve-up (~9.6 MB total)
    char* ws = (char*)d_ws;
    _Float16* xh   = (_Float16*)ws;                    // 8,388,608 B
    u32*      gk1  = (u32*)(ws + 8388608);             //   524,288 B
    u32*      gk2  = (u32*)(ws + 8912896);             //   524,288 B
    double*   sq64 = (double*)(ws + 9437184);          //   131,072 B
    float*    sqf  = (float*)(ws + 9568256);           //    65,536 B

    // 128 KB dynamic LDS needs the attribute raised (host-side, capture-safe).
    hipFuncSetAttribute(reinterpret_cast<const void*>(gram_topk_kernel),
                        hipFuncAttributeMaxDynamicSharedMemorySize, 131072);

    pre_kernel<<<dim3(32, 8), dim3(256), 0, stream>>>(x, xh, sq64, sqf);
    gram_topk_kernel<<<dim3(512), dim3(512), 131072, stream>>>(xh, sqf, gk1, gk2);
    tail_kernel<<<dim3(32, 8), dim3(256), 0, stream>>>(gk1, gk2, sq64, x, emb, out);
}